// Round 1
// 485.168 us; speedup vs baseline: 1.0411x; 1.0411x over previous
//
#include <hip/hip_runtime.h>

#define HIDDEN  128
#define REDUCED 64
#define NGRAPHS 4096

typedef float f4 __attribute__((ext_vector_type(4)));

// ---------------------------------------------------------------------------
// Kernel 1: fused segment-sum pool + squeeze-excite MLP. batch is SORTED, so
// graph g's nodes form a contiguous range found by binary search. One block
// (128 thr) per graph. Pool: thread t -> row-slot r = t>>5 (4 rows in
// flight), col c = t&31 (float4). Then the same block runs the MLP on the
// pooled row it already holds in LDS and writes y directly — the `pooled`
// global round-trip and a kernel launch are gone.
// The two binary searches live in DIFFERENT waves (t==0 / t==64) so their
// ~19 dependent latency-bound loads overlap instead of serializing under
// divergence in one wave.
// x loads here are NORMAL (cache-allocating): x is 244 MiB and fits the
// 256 MiB Infinity Cache — we deliberately leave it resident for kernel 2.
// ---------------------------------------------------------------------------
__global__ void pool_mlp_kernel(const float* __restrict__ x,
                                const int* __restrict__ batch,
                                const float* __restrict__ W1, const float* __restrict__ b1,
                                const float* __restrict__ W2, const float* __restrict__ b2,
                                float* __restrict__ y, int n_nodes) {
    const int g = blockIdx.x;
    const int t = threadIdx.x;  // 128
    __shared__ int s_range[2];
    if (t == 0) {
        int lo = 0, hi = n_nodes;
        while (lo < hi) { int mid = (lo + hi) >> 1; if (batch[mid] <  g) lo = mid + 1; else hi = mid; }
        s_range[0] = lo;
    } else if (t == 64) {
        int lo = 0, hi = n_nodes;
        while (lo < hi) { int mid = (lo + hi) >> 1; if (batch[mid] <= g) lo = mid + 1; else hi = mid; }
        s_range[1] = lo;
    }
    __syncthreads();
    const int lo = s_range[0], hi = s_range[1];
    const int r = t >> 5, c = t & 31;

    // ---- pool: same accumulation order as the verified baseline ----
    f4 acc = {0.f, 0.f, 0.f, 0.f};
    for (int n = lo + r; n < hi; n += 4) {
        const f4 v = ((const f4*)(x + (size_t)n * HIDDEN))[c];
        acc += v;
    }
    __shared__ f4 red[4][32];
    __shared__ float p_s[HIDDEN];
    __shared__ float h_s[REDUCED];
    red[r][c] = acc;
    __syncthreads();
    if (r == 0) {
        const f4 a = red[0][c], b = red[1][c], d = red[2][c], e = red[3][c];
        f4 s;
        s.x = a.x + b.x + d.x + e.x;
        s.y = a.y + b.y + d.y + e.y;
        s.z = a.z + b.z + d.z + e.z;
        s.w = a.w + b.w + d.w + e.w;
        ((f4*)p_s)[c] = s;
    }
    __syncthreads();

    // ---- MLP: h = relu(p @ W1 + b1) [64]; y = sigmoid(h @ W2 + b2) [128].
    // W1/W2 (48 KB) stay L2-resident across the 4096 blocks.
    if (t < REDUCED) {
        float a1 = b1[t];
        #pragma unroll 8
        for (int i = 0; i < HIDDEN; ++i) a1 = fmaf(p_s[i], W1[i * REDUCED + t], a1);
        h_s[t] = a1 > 0.f ? a1 : 0.f;
    }
    __syncthreads();
    float a2 = b2[t];
    #pragma unroll 8
    for (int j = 0; j < REDUCED; ++j) a2 = fmaf(h_s[j], W2[j * HIDDEN + t], a2);
    y[(size_t)g * HIDDEN + t] = 1.f / (1.f + __expf(-a2));
}

// ---------------------------------------------------------------------------
// Kernel 2: out[n] = x[n] * y[batch[n]] — pure-bandwidth float4 elementwise.
// 32 consecutive threads share one node -> batch[n] load broadcasts; y row
// (2 MB table) stays L2-resident.
// KEY CHANGE: out stores are NON-TEMPORAL (no L3 allocation) and the x
// re-read is a non-temporal load (x is dead afterwards, no need to
// re-allocate). This stops the 244 MiB out-stream from evicting the
// L3-resident copy of x that kernel 1 just created, so the second pass over
// x is served from Infinity Cache instead of HBM -> modulate becomes
// write-bound (~42 us) instead of read+write bound (~81 us).
// ---------------------------------------------------------------------------
__global__ void modulate_kernel(const float* __restrict__ x,
                                const int* __restrict__ batch,
                                const float* __restrict__ y,
                                float* __restrict__ out, long long total4) {
    const long long idx = (long long)blockIdx.x * blockDim.x + threadIdx.x;
    if (idx >= total4) return;
    const long long n = idx >> 5;   // node
    const int c = (int)(idx & 31);  // float4 column
    const int g = batch[n];
    const f4 xv = __builtin_nontemporal_load((const f4*)x + idx);
    const f4 yv = ((const f4*)y)[(size_t)g * (HIDDEN / 4) + c];
    f4 o;
    o.x = xv.x * yv.x; o.y = xv.y * yv.y; o.z = xv.z * yv.z; o.w = xv.w * yv.w;
    __builtin_nontemporal_store(o, (f4*)out + idx);
}

extern "C" void kernel_launch(void* const* d_in, const int* in_sizes, int n_in,
                              void* d_out, int out_size, void* d_ws, size_t ws_size,
                              hipStream_t stream) {
    const float* x     = (const float*)d_in[0];
    const int*   batch = (const int*)d_in[1];
    // d_in[2] is the scalar `size` (4096) — fixed-shape problem, hardcoded.
    const float* W1 = (const float*)d_in[3];
    const float* b1 = (const float*)d_in[4];
    const float* W2 = (const float*)d_in[5];
    const float* b2 = (const float*)d_in[6];
    float* out = (float*)d_out;

    const int n_nodes = in_sizes[0] / HIDDEN;

    float* y = (float*)d_ws;  // 4096*128*4 = 2 MB (fully written; poison-safe)

    pool_mlp_kernel<<<NGRAPHS, 128, 0, stream>>>(x, batch, W1, b1, W2, b2, y, n_nodes);

    const long long total4 = (long long)n_nodes * (HIDDEN / 4);
    const int blocks = (int)((total4 + 255) / 256);
    modulate_kernel<<<blocks, 256, 0, stream>>>(x, batch, y, out, total4);
}